// Round 10
// baseline (226.768 us; speedup 1.0000x reference)
//
#include <hip/hip_runtime.h>

#define N_NODES 100000
#define N_EDGES 2000000

typedef __bf16 bf16x8 __attribute__((ext_vector_type(8)));
typedef float f32x4 __attribute__((ext_vector_type(4)));
typedef float f32x16 __attribute__((ext_vector_type(16)));

#define AS1 __attribute__((address_space(1)))
#define AS3 __attribute__((address_space(3)))

struct TrueTag { static constexpr bool value = true; };
struct FalseTag { static constexpr bool value = false; };

__device__ __forceinline__ unsigned f2bf_rne(float f) {
  unsigned u = __builtin_bit_cast(unsigned, f);
  u += 0x7FFFu + ((u >> 16) & 1u);
  return u >> 16;
}

// Pack two NON-NEGATIVE f32 into bf16x2, round-half-up.
__device__ __forceinline__ unsigned pack_rhu(float lo, float hi) {
  unsigned ulo = __builtin_bit_cast(unsigned, lo) + 0x8000u;
  unsigned uhi = __builtin_bit_cast(unsigned, hi) + 0x8000u;
  return __builtin_amdgcn_perm(uhi, ulo, 0x07060302u);
}

// |a-b| on a packed bf16 pair -> packed bf16 pair.
__device__ __forceinline__ unsigned absdiff_pack(unsigned a, unsigned b) {
  float alo = __builtin_bit_cast(float, a << 16);
  float ahi = __builtin_bit_cast(float, a & 0xFFFF0000u);
  float blo = __builtin_bit_cast(float, b << 16);
  float bhi = __builtin_bit_cast(float, b & 0xFFFF0000u);
  return pack_rhu(fabsf(alo - blo), fabsf(ahi - bhi));
}

// ---------------------------------------------------------------------------
// Node MLP via MFMA (proven math). Grid bumped 1024 -> 3125 blocks
// (2 tiles/block, ~3 waves/SIMD instead of 1) for latency hiding; the
// per-block weight-setup cost is amortized over 2 tiles and the extra
// redundant weight reads (~2MB) are trivial.
// ---------------------------------------------------------------------------
__global__ __launch_bounds__(64, 1) void node_mfma_kernel(
    const float* __restrict__ X, const float* __restrict__ W1,
    const float* __restrict__ b1, const float* __restrict__ W2,
    const float* __restrict__ b2, unsigned short* __restrict__ H) {
  const int lane = threadIdx.x;
  const int l15 = lane & 15;
  const int quad = lane >> 4;

  float w1v[2][4][8], b1v[2][8];
#pragma unroll
  for (int c = 0; c < 2; ++c)
#pragma unroll
    for (int j = 0; j < 8; ++j) {
      int col = c * 32 + quad * 8 + j;
      b1v[c][j] = b1[col];
#pragma unroll
      for (int d = 0; d < 4; ++d) w1v[c][d][j] = W1[d * 64 + col];
    }

  uint4 afr[2][4];
#pragma unroll
  for (int c = 0; c < 2; ++c)
#pragma unroll
    for (int mt = 0; mt < 4; ++mt) {
      unsigned w[4];
#pragma unroll
      for (int p = 0; p < 4; ++p) {
        int k = c * 32 + quad * 8 + 2 * p;
        unsigned lo = f2bf_rne(W2[k * 64 + mt * 16 + l15]);
        unsigned hi = f2bf_rne(W2[(k + 1) * 64 + mt * 16 + l15]);
        w[p] = lo | (hi << 16);
      }
      afr[c][mt] = make_uint4(w[0], w[1], w[2], w[3]);
    }
  float b2v[16];
#pragma unroll
  for (int mt = 0; mt < 4; ++mt)
#pragma unroll
    for (int r = 0; r < 4; ++r) b2v[mt * 4 + r] = b2[mt * 16 + quad * 4 + r];

  const int ntiles = N_NODES / 16;  // 6250
  for (int tile = blockIdx.x; tile < ntiles; tile += gridDim.x) {
    float4 xv = ((const float4*)X)[tile * 16 + l15];

    uint4 bfr[2];
#pragma unroll
    for (int c = 0; c < 2; ++c) {
      unsigned w[4];
#pragma unroll
      for (int p = 0; p < 4; ++p) {
        float h0 = fmaxf(b1v[c][2 * p] + xv.x * w1v[c][0][2 * p] +
                             xv.y * w1v[c][1][2 * p] + xv.z * w1v[c][2][2 * p] +
                             xv.w * w1v[c][3][2 * p],
                         0.f);
        float h1 = fmaxf(b1v[c][2 * p + 1] + xv.x * w1v[c][0][2 * p + 1] +
                             xv.y * w1v[c][1][2 * p + 1] +
                             xv.z * w1v[c][2][2 * p + 1] +
                             xv.w * w1v[c][3][2 * p + 1],
                         0.f);
        w[p] = pack_rhu(h0, h1);
      }
      bfr[c] = make_uint4(w[0], w[1], w[2], w[3]);
    }

    f32x4 acc[4];
#pragma unroll
    for (int mt = 0; mt < 4; ++mt) acc[mt] = (f32x4){0.f, 0.f, 0.f, 0.f};
#pragma unroll
    for (int c = 0; c < 2; ++c)
#pragma unroll
      for (int mt = 0; mt < 4; ++mt)
        acc[mt] = __builtin_amdgcn_mfma_f32_16x16x32_bf16(
            __builtin_bit_cast(bf16x8, afr[c][mt]),
            __builtin_bit_cast(bf16x8, bfr[c]), acc[mt], 0, 0, 0);

    unsigned short* hrow = H + (tile * 16 + l15) * 64;
#pragma unroll
    for (int mt = 0; mt < 4; ++mt) {
      unsigned lo = pack_rhu(fmaxf(acc[mt][0] + b2v[mt * 4 + 0], 0.f),
                             fmaxf(acc[mt][1] + b2v[mt * 4 + 1], 0.f));
      unsigned hi = pack_rhu(fmaxf(acc[mt][2] + b2v[mt * 4 + 2], 0.f),
                             fmaxf(acc[mt][3] + b2v[mt * 4 + 3], 0.f));
      *(uint2*)(hrow + mt * 16 + quad * 4) = make_uint2(lo, hi);
    }
  }
}

// ---------------------------------------------------------------------------
// Edge MLP v9: r8's proven per-wave structure (71.5us: staged coalesced
// gathers, single 8KB buffer/wave, vmcnt(4)/vmcnt(5), 6-reg/6-LDS weight
// split, absdiff math) at 4 WAVES/SIMD via 512-thread blocks.
//
// r9 post-mortem: pk-minmax cut VALUBusy 57->36 but time got WORSE (+spill)
// -> VALU issue is not the critical path; both pipes <=38% at occupancy 27%
// -> still latency-bound. r7->r8 showed near-linear scaling with waves/SIMD
// (2->3 waves = 88->71.5us). The r8 structure is register-light (VGPR 76)
// but its 44.5KB LDS/block capped 256-thread blocks at 3/CU. Merging two
// blocks into one 512-thread block shares the 12.3KB weight LDS: 8x8KB
// buffers + 12.3KB = 76.25KB/block -> 2 blocks/CU = 16 waves/CU =
// 4 waves/SIMD (152.5 <= 160KB). __launch_bounds__(512,4) caps VGPR at 128;
// r8 needed 76 -> no spill. Per-wave code is byte-identical to r8.
// ---------------------------------------------------------------------------
__global__ __launch_bounds__(512, 4) void edge_mlp_kernel(
    const unsigned short* __restrict__ H, const int* __restrict__ pairs,
    const float* __restrict__ We1, const float* __restrict__ be1,
    const float* __restrict__ We2, const float* __restrict__ be2,
    float* __restrict__ out) {
  __shared__ uint4 gbuf[8][512];      // 64 KB: one 8KB row buffer per wave
  __shared__ uint4 lds_w6[6][2][64];  // 12 KB: We1^T chunks 6..11
  __shared__ float lds_c[64];         // 256 B: We2 (epilogue broadcast)

  const int tid = threadIdx.x;
  const int lane = tid & 63;
  const int n = lane & 31;       // edge within tile (readback role)
  const int half = lane >> 5;    // k-half (readback role)
  const int wave = tid >> 6;     // 0..7
  const int rowsel = lane >> 3;  // loader role: row within 8-row group
  const int swzc = (lane & 7) ^ rowsel;  // global 16B chunk to fetch

  if (tid < 64) lds_c[tid] = We2[tid];

  // Stage We1^T chunks 6..11 to LDS cooperatively (waves 0..3, 3 items each).
  // lds_w6[c-6][mt][lane] elem j = bf16(We1[(c*16+half*8+j)*64 + mt*32+n]).
  if (wave < 4) {
#pragma unroll
    for (int i = 0; i < 3; ++i) {
      const int idx = wave * 3 + i;  // 0..11
      const int c = 6 + (idx >> 1);
      const int mt = idx & 1;
      const int col = mt * 32 + n;
      const int kb = c * 16 + half * 8;
      unsigned w[4];
#pragma unroll
      for (int p = 0; p < 4; ++p)
        w[p] = f2bf_rne(We1[(kb + 2 * p) * 64 + col]) |
               (f2bf_rne(We1[(kb + 2 * p + 1) * 64 + col]) << 16);
      lds_w6[c - 6][mt][lane] = make_uint4(w[0], w[1], w[2], w[3]);
    }
  }

  // We1^T chunks 0..5 in registers (48 VGPRs).
  uint4 afr[6][2];
#pragma unroll
  for (int c = 0; c < 6; ++c)
#pragma unroll
    for (int mt = 0; mt < 2; ++mt) {
      const int col = mt * 32 + n;
      const int kb = c * 16 + half * 8;
      unsigned w[4];
#pragma unroll
      for (int p = 0; p < 4; ++p)
        w[p] = f2bf_rne(We1[(kb + 2 * p) * 64 + col]) |
               (f2bf_rne(We1[(kb + 2 * p + 1) * 64 + col]) << 16);
      afr[c][mt] = make_uint4(w[0], w[1], w[2], w[3]);
    }
  // Bias chunk: only elem0 nonzero -> 2 regs.
  unsigned a12[2];
#pragma unroll
  for (int mt = 0; mt < 2; ++mt)
    a12[mt] = (half == 0) ? f2bf_rne(be1[mt * 32 + n]) : 0u;
  const uint4 b13u = make_uint4((half == 0) ? 0x00003F80u : 0u, 0u, 0u, 0u);
  const float be2v = be2[0];

  uint4* const buf = &gbuf[wave][0];
  int rbo[4];
#pragma unroll
  for (int c = 0; c < 4; ++c) rbo[c] = n * 8 + ((2 * c + half) ^ (n & 7));

  const int wid = blockIdx.x * 8 + wave;
  const int nw = gridDim.x * 8;  // 4096
  const int ntiles = N_EDGES / 32;
  const int last = ntiles - 1;
  const int2* pairs2 = (const int2*)pairs;

  // Weights visible to all waves; also drains vmem -> clean vmcnt state.
  __syncthreads();

  // Issue the 8 row-group gathers for one tile into buffer `dst`.
  auto issue_gathers = [&](uint4* dst, const int2* prs) {
#pragma unroll
    for (int k = 0; k < 4; ++k) {
      const AS1 unsigned* gu =
          (const AS1 unsigned*)(H + (size_t)prs[k].x * 64) + swzc * 4;
      const AS1 unsigned* gv =
          (const AS1 unsigned*)(H + (size_t)prs[k].y * 64) + swzc * 4;
      __builtin_amdgcn_global_load_lds(gu, (AS3 unsigned*)(dst + k * 64), 16,
                                       0, 0);
      __builtin_amdgcn_global_load_lds(
          gv, (AS3 unsigned*)(dst + 256 + k * 64), 16, 0, 0);
    }
  };

  // Prologue: gathers(t0) [8], then pairs(t1) [4] => 12 outstanding at iter0
  // -> vmcnt(4) retires exactly the 8 gathers.
  int2 pr[4];
  {
#pragma unroll
    for (int k = 0; k < 4; ++k) pr[k] = pairs2[wid * 32 + k * 8 + rowsel];
    issue_gathers(buf, pr);
    __builtin_amdgcn_sched_barrier(0);
    int t1 = wid + nw <= last ? wid + nw : last;
#pragma unroll
    for (int k = 0; k < 4; ++k) pr[k] = pairs2[t1 * 32 + k * 8 + rowsel];
  }

  // One tile: wait own gathers -> read rows to regs -> refill same buffer
  // for t+nw -> reload pr for t+2nw -> absdiff -> 26 MFMAs -> epilogue.
  auto body = [&](int tc, auto FIRST) {
    __builtin_amdgcn_sched_barrier(0);
    if constexpr (decltype(FIRST)::value)
      __builtin_amdgcn_s_waitcnt(0x0F74);  // vmcnt(4): iter0, no prior store
    else
      __builtin_amdgcn_s_waitcnt(0x0F75);  // vmcnt(5): steady state
    __builtin_amdgcn_sched_barrier(0);

    const int t = tc <= last ? tc : last;
    uint4 hu[4], hv[4];
#pragma unroll
    for (int c = 0; c < 4; ++c) {
      hu[c] = buf[rbo[c]];
      hv[c] = buf[256 + rbo[c]];
    }
    // Rows now (being) read to regs; fence completion, then reuse buffer.
    asm volatile("s_waitcnt lgkmcnt(0)" ::: "memory");
    __builtin_amdgcn_sched_barrier(0);
    issue_gathers(buf, pr);  // tile tc+nw, ~full tile of compute ahead
    __builtin_amdgcn_sched_barrier(0);  // pin: gathers before pairs loads
    {
      int tn = tc + 2 * nw <= last ? tc + 2 * nw : last;
#pragma unroll
      for (int k = 0; k < 4; ++k) pr[k] = pairs2[tn * 32 + k * 8 + rowsel];
    }

    uint4 ab[4];
#pragma unroll
    for (int c = 0; c < 4; ++c) {
      ab[c].x = absdiff_pack(hu[c].x, hv[c].x);
      ab[c].y = absdiff_pack(hu[c].y, hv[c].y);
      ab[c].z = absdiff_pack(hu[c].z, hv[c].z);
      ab[c].w = absdiff_pack(hu[c].w, hv[c].w);
    }

    f32x16 acc[2];
    acc[0] = (f32x16)(0.f);
    acc[1] = (f32x16)(0.f);
    // Chunks 0..3: hu, A from regs.
#pragma unroll
    for (int c = 0; c < 4; ++c) {
      const bf16x8 b = __builtin_bit_cast(bf16x8, hu[c]);
#pragma unroll
      for (int mt = 0; mt < 2; ++mt)
        acc[mt] = __builtin_amdgcn_mfma_f32_32x32x16_bf16(
            __builtin_bit_cast(bf16x8, afr[c][mt]), b, acc[mt], 0, 0, 0);
    }
    // Chunks 4..5: hv[0..1], A from regs.
#pragma unroll
    for (int c = 0; c < 2; ++c) {
      const bf16x8 b = __builtin_bit_cast(bf16x8, hv[c]);
#pragma unroll
      for (int mt = 0; mt < 2; ++mt)
        acc[mt] = __builtin_amdgcn_mfma_f32_32x32x16_bf16(
            __builtin_bit_cast(bf16x8, afr[4 + c][mt]), b, acc[mt], 0, 0, 0);
    }
    // Chunks 6..7: hv[2..3], A just-in-time from LDS.
#pragma unroll
    for (int c = 0; c < 2; ++c) {
      const bf16x8 b = __builtin_bit_cast(bf16x8, hv[2 + c]);
#pragma unroll
      for (int mt = 0; mt < 2; ++mt) {
        const uint4 a = lds_w6[c][mt][lane];
        acc[mt] = __builtin_amdgcn_mfma_f32_32x32x16_bf16(
            __builtin_bit_cast(bf16x8, a), b, acc[mt], 0, 0, 0);
      }
    }
    // Chunks 8..11: |hu-hv|, A just-in-time from LDS.
#pragma unroll
    for (int c = 0; c < 4; ++c) {
      const bf16x8 b = __builtin_bit_cast(bf16x8, ab[c]);
#pragma unroll
      for (int mt = 0; mt < 2; ++mt) {
        const uint4 a = lds_w6[2 + c][mt][lane];
        acc[mt] = __builtin_amdgcn_mfma_f32_32x32x16_bf16(
            __builtin_bit_cast(bf16x8, a), b, acc[mt], 0, 0, 0);
      }
    }
    // Chunk 12: bias.
#pragma unroll
    for (int mt = 0; mt < 2; ++mt)
      acc[mt] = __builtin_amdgcn_mfma_f32_32x32x16_bf16(
          __builtin_bit_cast(bf16x8, make_uint4(a12[mt], 0u, 0u, 0u)),
          __builtin_bit_cast(bf16x8, b13u), acc[mt], 0, 0, 0);

    // Epilogue: relu + We2 dot (We2 broadcast from LDS).
    // acc[mt][4g+q] -> hidden row o = mt*32 + q + 8g + 4*half.
    float s = 0.f;
#pragma unroll
    for (int mt = 0; mt < 2; ++mt)
#pragma unroll
      for (int g = 0; g < 4; ++g) {
        const float4 ew = *(const float4*)&lds_c[mt * 32 + g * 8 + 4 * half];
        s += fmaxf(acc[mt][4 * g + 0], 0.f) * ew.x;
        s += fmaxf(acc[mt][4 * g + 1], 0.f) * ew.y;
        s += fmaxf(acc[mt][4 * g + 2], 0.f) * ew.z;
        s += fmaxf(acc[mt][4 * g + 3], 0.f) * ew.w;
      }
    s += __shfl_xor(s, 32);
    if (half == 0) out[t * 32 + n] = s + be2v;
  };

  int t = wid;
  body(t, TrueTag{});
  for (t += nw; t < ntiles; t += nw) body(t, FalseTag{});
}

extern "C" void kernel_launch(void* const* d_in, const int* in_sizes, int n_in,
                              void* d_out, int out_size, void* d_ws,
                              size_t ws_size, hipStream_t stream) {
  const float* X = (const float*)d_in[0];
  const int* pairs = (const int*)d_in[1];
  const float* W1 = (const float*)d_in[2];
  const float* b1 = (const float*)d_in[3];
  const float* W2 = (const float*)d_in[4];
  const float* b2 = (const float*)d_in[5];
  const float* We1 = (const float*)d_in[6];
  const float* be1 = (const float*)d_in[7];
  const float* We2 = (const float*)d_in[8];
  const float* be2 = (const float*)d_in[9];
  float* out = (float*)d_out;
  unsigned short* H = (unsigned short*)d_ws;  // 100000*64 bf16 = 12.8 MB

  node_mfma_kernel<<<3125, 64, 0, stream>>>(X, W1, b1, W2, b2, H);
  // 76.25 KB LDS/block, VGPR cap 128 (r8 used 76) -> 2 blocks/CU,
  // 16 waves/CU, 4 waves/SIMD. 512 blocks = exactly resident.
  edge_mlp_kernel<<<512, 512, 0, stream>>>(H, pairs, We1, be1, We2, be2, out);
}

// Round 11
// 160.981 us; speedup vs baseline: 1.4087x; 1.4087x over previous
//
#include <hip/hip_runtime.h>

#define N_NODES 100000
#define N_EDGES 2000000

typedef __bf16 bf16x8 __attribute__((ext_vector_type(8)));
typedef float f32x4 __attribute__((ext_vector_type(4)));
typedef float f32x16 __attribute__((ext_vector_type(16)));

#define AS1 __attribute__((address_space(1)))
#define AS3 __attribute__((address_space(3)))

struct TrueTag { static constexpr bool value = true; };
struct FalseTag { static constexpr bool value = false; };

__device__ __forceinline__ unsigned f2bf_rne(float f) {
  unsigned u = __builtin_bit_cast(unsigned, f);
  u += 0x7FFFu + ((u >> 16) & 1u);
  return u >> 16;
}

// Pack two NON-NEGATIVE f32 into bf16x2, round-half-up.
__device__ __forceinline__ unsigned pack_rhu(float lo, float hi) {
  unsigned ulo = __builtin_bit_cast(unsigned, lo) + 0x8000u;
  unsigned uhi = __builtin_bit_cast(unsigned, hi) + 0x8000u;
  return __builtin_amdgcn_perm(uhi, ulo, 0x07060302u);
}

// |a-b| on a packed bf16 pair -> packed bf16 pair.
__device__ __forceinline__ unsigned absdiff_pack(unsigned a, unsigned b) {
  float alo = __builtin_bit_cast(float, a << 16);
  float ahi = __builtin_bit_cast(float, a & 0xFFFF0000u);
  float blo = __builtin_bit_cast(float, b << 16);
  float bhi = __builtin_bit_cast(float, b & 0xFFFF0000u);
  return pack_rhu(fabsf(alo - blo), fabsf(ahi - bhi));
}

// ---------------------------------------------------------------------------
// Node MLP via MFMA (proven math), 3125 blocks (2 tiles/block).
// ---------------------------------------------------------------------------
__global__ __launch_bounds__(64, 1) void node_mfma_kernel(
    const float* __restrict__ X, const float* __restrict__ W1,
    const float* __restrict__ b1, const float* __restrict__ W2,
    const float* __restrict__ b2, unsigned short* __restrict__ H) {
  const int lane = threadIdx.x;
  const int l15 = lane & 15;
  const int quad = lane >> 4;

  float w1v[2][4][8], b1v[2][8];
#pragma unroll
  for (int c = 0; c < 2; ++c)
#pragma unroll
    for (int j = 0; j < 8; ++j) {
      int col = c * 32 + quad * 8 + j;
      b1v[c][j] = b1[col];
#pragma unroll
      for (int d = 0; d < 4; ++d) w1v[c][d][j] = W1[d * 64 + col];
    }

  uint4 afr[2][4];
#pragma unroll
  for (int c = 0; c < 2; ++c)
#pragma unroll
    for (int mt = 0; mt < 4; ++mt) {
      unsigned w[4];
#pragma unroll
      for (int p = 0; p < 4; ++p) {
        int k = c * 32 + quad * 8 + 2 * p;
        unsigned lo = f2bf_rne(W2[k * 64 + mt * 16 + l15]);
        unsigned hi = f2bf_rne(W2[(k + 1) * 64 + mt * 16 + l15]);
        w[p] = lo | (hi << 16);
      }
      afr[c][mt] = make_uint4(w[0], w[1], w[2], w[3]);
    }
  float b2v[16];
#pragma unroll
  for (int mt = 0; mt < 4; ++mt)
#pragma unroll
    for (int r = 0; r < 4; ++r) b2v[mt * 4 + r] = b2[mt * 16 + quad * 4 + r];

  const int ntiles = N_NODES / 16;  // 6250
  for (int tile = blockIdx.x; tile < ntiles; tile += gridDim.x) {
    float4 xv = ((const float4*)X)[tile * 16 + l15];

    uint4 bfr[2];
#pragma unroll
    for (int c = 0; c < 2; ++c) {
      unsigned w[4];
#pragma unroll
      for (int p = 0; p < 4; ++p) {
        float h0 = fmaxf(b1v[c][2 * p] + xv.x * w1v[c][0][2 * p] +
                             xv.y * w1v[c][1][2 * p] + xv.z * w1v[c][2][2 * p] +
                             xv.w * w1v[c][3][2 * p],
                         0.f);
        float h1 = fmaxf(b1v[c][2 * p + 1] + xv.x * w1v[c][0][2 * p + 1] +
                             xv.y * w1v[c][1][2 * p + 1] +
                             xv.z * w1v[c][2][2 * p + 1] +
                             xv.w * w1v[c][3][2 * p + 1],
                         0.f);
        w[p] = pack_rhu(h0, h1);
      }
      bfr[c] = make_uint4(w[0], w[1], w[2], w[3]);
    }

    f32x4 acc[4];
#pragma unroll
    for (int mt = 0; mt < 4; ++mt) acc[mt] = (f32x4){0.f, 0.f, 0.f, 0.f};
#pragma unroll
    for (int c = 0; c < 2; ++c)
#pragma unroll
      for (int mt = 0; mt < 4; ++mt)
        acc[mt] = __builtin_amdgcn_mfma_f32_16x16x32_bf16(
            __builtin_bit_cast(bf16x8, afr[c][mt]),
            __builtin_bit_cast(bf16x8, bfr[c]), acc[mt], 0, 0, 0);

    unsigned short* hrow = H + (tile * 16 + l15) * 64;
#pragma unroll
    for (int mt = 0; mt < 4; ++mt) {
      unsigned lo = pack_rhu(fmaxf(acc[mt][0] + b2v[mt * 4 + 0], 0.f),
                             fmaxf(acc[mt][1] + b2v[mt * 4 + 1], 0.f));
      unsigned hi = pack_rhu(fmaxf(acc[mt][2] + b2v[mt * 4 + 2], 0.f),
                             fmaxf(acc[mt][3] + b2v[mt * 4 + 3], 0.f));
      *(uint2*)(hrow + mt * 16 + quad * 4) = make_uint2(lo, hi);
    }
  }
}

// ---------------------------------------------------------------------------
// Edge MLP v10: r10's 512-thread / 16-waves-per-CU geometry with the
// register-allocator pressure REMOVED.
//
// r10 post-mortem: __launch_bounds__(512,4) forced a 128-total-VGPR budget;
// after 32 AGPR acc the allocator cut arch regs to 64 and spilled the 48-reg
// afr weight array to scratch (FETCH 183->452MB, WRITE 7.8->54MB) -- the
// regression was pure spill, occupancy itself reached 43%. The code only
// NEEDS ~108 total regs (r8: arch 76 + acc 32), which already fits the
// 128/wave required for 4 waves/SIMD. So: __launch_bounds__(512,3) gives the
// allocator a ~170 budget (no spill, same codegen as r8's proven (256,3)),
// and the HARDWARE still reaches 4 waves/SIMD because actual usage <= 128
// and LDS (76.25KB/block) allows exactly 2 blocks/CU. Worst case the
// allocator drifts past 128 -> 3 waves/SIMD = r8 occupancy (bounded
// downside). Everything else byte-identical to r10/r8.
// ---------------------------------------------------------------------------
__global__ __launch_bounds__(512, 3) void edge_mlp_kernel(
    const unsigned short* __restrict__ H, const int* __restrict__ pairs,
    const float* __restrict__ We1, const float* __restrict__ be1,
    const float* __restrict__ We2, const float* __restrict__ be2,
    float* __restrict__ out) {
  __shared__ uint4 gbuf[8][512];      // 64 KB: one 8KB row buffer per wave
  __shared__ uint4 lds_w6[6][2][64];  // 12 KB: We1^T chunks 6..11
  __shared__ float lds_c[64];         // 256 B: We2 (epilogue broadcast)

  const int tid = threadIdx.x;
  const int lane = tid & 63;
  const int n = lane & 31;       // edge within tile (readback role)
  const int half = lane >> 5;    // k-half (readback role)
  const int wave = tid >> 6;     // 0..7
  const int rowsel = lane >> 3;  // loader role: row within 8-row group
  const int swzc = (lane & 7) ^ rowsel;  // global 16B chunk to fetch

  if (tid < 64) lds_c[tid] = We2[tid];

  // Stage We1^T chunks 6..11 to LDS cooperatively (waves 0..3, 3 items each).
  // lds_w6[c-6][mt][lane] elem j = bf16(We1[(c*16+half*8+j)*64 + mt*32+n]).
  if (wave < 4) {
#pragma unroll
    for (int i = 0; i < 3; ++i) {
      const int idx = wave * 3 + i;  // 0..11
      const int c = 6 + (idx >> 1);
      const int mt = idx & 1;
      const int col = mt * 32 + n;
      const int kb = c * 16 + half * 8;
      unsigned w[4];
#pragma unroll
      for (int p = 0; p < 4; ++p)
        w[p] = f2bf_rne(We1[(kb + 2 * p) * 64 + col]) |
               (f2bf_rne(We1[(kb + 2 * p + 1) * 64 + col]) << 16);
      lds_w6[c - 6][mt][lane] = make_uint4(w[0], w[1], w[2], w[3]);
    }
  }

  // We1^T chunks 0..5 in registers (48 VGPRs).
  uint4 afr[6][2];
#pragma unroll
  for (int c = 0; c < 6; ++c)
#pragma unroll
    for (int mt = 0; mt < 2; ++mt) {
      const int col = mt * 32 + n;
      const int kb = c * 16 + half * 8;
      unsigned w[4];
#pragma unroll
      for (int p = 0; p < 4; ++p)
        w[p] = f2bf_rne(We1[(kb + 2 * p) * 64 + col]) |
               (f2bf_rne(We1[(kb + 2 * p + 1) * 64 + col]) << 16);
      afr[c][mt] = make_uint4(w[0], w[1], w[2], w[3]);
    }
  // Bias chunk: only elem0 nonzero -> 2 regs.
  unsigned a12[2];
#pragma unroll
  for (int mt = 0; mt < 2; ++mt)
    a12[mt] = (half == 0) ? f2bf_rne(be1[mt * 32 + n]) : 0u;
  const uint4 b13u = make_uint4((half == 0) ? 0x00003F80u : 0u, 0u, 0u, 0u);
  const float be2v = be2[0];

  uint4* const buf = &gbuf[wave][0];
  int rbo[4];
#pragma unroll
  for (int c = 0; c < 4; ++c) rbo[c] = n * 8 + ((2 * c + half) ^ (n & 7));

  const int wid = blockIdx.x * 8 + wave;
  const int nw = gridDim.x * 8;  // 4096
  const int ntiles = N_EDGES / 32;
  const int last = ntiles - 1;
  const int2* pairs2 = (const int2*)pairs;

  // Weights visible to all waves; also drains vmem -> clean vmcnt state.
  __syncthreads();

  // Issue the 8 row-group gathers for one tile into buffer `dst`.
  auto issue_gathers = [&](uint4* dst, const int2* prs) {
#pragma unroll
    for (int k = 0; k < 4; ++k) {
      const AS1 unsigned* gu =
          (const AS1 unsigned*)(H + (size_t)prs[k].x * 64) + swzc * 4;
      const AS1 unsigned* gv =
          (const AS1 unsigned*)(H + (size_t)prs[k].y * 64) + swzc * 4;
      __builtin_amdgcn_global_load_lds(gu, (AS3 unsigned*)(dst + k * 64), 16,
                                       0, 0);
      __builtin_amdgcn_global_load_lds(
          gv, (AS3 unsigned*)(dst + 256 + k * 64), 16, 0, 0);
    }
  };

  // Prologue: gathers(t0) [8], then pairs(t1) [4] => 12 outstanding at iter0
  // -> vmcnt(4) retires exactly the 8 gathers.
  int2 pr[4];
  {
#pragma unroll
    for (int k = 0; k < 4; ++k) pr[k] = pairs2[wid * 32 + k * 8 + rowsel];
    issue_gathers(buf, pr);
    __builtin_amdgcn_sched_barrier(0);
    int t1 = wid + nw <= last ? wid + nw : last;
#pragma unroll
    for (int k = 0; k < 4; ++k) pr[k] = pairs2[t1 * 32 + k * 8 + rowsel];
  }

  // One tile: wait own gathers -> read rows to regs -> refill same buffer
  // for t+nw -> reload pr for t+2nw -> absdiff -> 26 MFMAs -> epilogue.
  auto body = [&](int tc, auto FIRST) {
    __builtin_amdgcn_sched_barrier(0);
    if constexpr (decltype(FIRST)::value)
      __builtin_amdgcn_s_waitcnt(0x0F74);  // vmcnt(4): iter0, no prior store
    else
      __builtin_amdgcn_s_waitcnt(0x0F75);  // vmcnt(5): steady state
    __builtin_amdgcn_sched_barrier(0);

    const int t = tc <= last ? tc : last;
    uint4 hu[4], hv[4];
#pragma unroll
    for (int c = 0; c < 4; ++c) {
      hu[c] = buf[rbo[c]];
      hv[c] = buf[256 + rbo[c]];
    }
    // Rows now (being) read to regs; fence completion, then reuse buffer.
    asm volatile("s_waitcnt lgkmcnt(0)" ::: "memory");
    __builtin_amdgcn_sched_barrier(0);
    issue_gathers(buf, pr);  // tile tc+nw, ~full tile of compute ahead
    __builtin_amdgcn_sched_barrier(0);  // pin: gathers before pairs loads
    {
      int tn = tc + 2 * nw <= last ? tc + 2 * nw : last;
#pragma unroll
      for (int k = 0; k < 4; ++k) pr[k] = pairs2[tn * 32 + k * 8 + rowsel];
    }

    uint4 ab[4];
#pragma unroll
    for (int c = 0; c < 4; ++c) {
      ab[c].x = absdiff_pack(hu[c].x, hv[c].x);
      ab[c].y = absdiff_pack(hu[c].y, hv[c].y);
      ab[c].z = absdiff_pack(hu[c].z, hv[c].z);
      ab[c].w = absdiff_pack(hu[c].w, hv[c].w);
    }

    f32x16 acc[2];
    acc[0] = (f32x16)(0.f);
    acc[1] = (f32x16)(0.f);
    // Chunks 0..3: hu, A from regs.
#pragma unroll
    for (int c = 0; c < 4; ++c) {
      const bf16x8 b = __builtin_bit_cast(bf16x8, hu[c]);
#pragma unroll
      for (int mt = 0; mt < 2; ++mt)
        acc[mt] = __builtin_amdgcn_mfma_f32_32x32x16_bf16(
            __builtin_bit_cast(bf16x8, afr[c][mt]), b, acc[mt], 0, 0, 0);
    }
    // Chunks 4..5: hv[0..1], A from regs.
#pragma unroll
    for (int c = 0; c < 2; ++c) {
      const bf16x8 b = __builtin_bit_cast(bf16x8, hv[c]);
#pragma unroll
      for (int mt = 0; mt < 2; ++mt)
        acc[mt] = __builtin_amdgcn_mfma_f32_32x32x16_bf16(
            __builtin_bit_cast(bf16x8, afr[4 + c][mt]), b, acc[mt], 0, 0, 0);
    }
    // Chunks 6..7: hv[2..3], A just-in-time from LDS.
#pragma unroll
    for (int c = 0; c < 2; ++c) {
      const bf16x8 b = __builtin_bit_cast(bf16x8, hv[2 + c]);
#pragma unroll
      for (int mt = 0; mt < 2; ++mt) {
        const uint4 a = lds_w6[c][mt][lane];
        acc[mt] = __builtin_amdgcn_mfma_f32_32x32x16_bf16(
            __builtin_bit_cast(bf16x8, a), b, acc[mt], 0, 0, 0);
      }
    }
    // Chunks 8..11: |hu-hv|, A just-in-time from LDS.
#pragma unroll
    for (int c = 0; c < 4; ++c) {
      const bf16x8 b = __builtin_bit_cast(bf16x8, ab[c]);
#pragma unroll
      for (int mt = 0; mt < 2; ++mt) {
        const uint4 a = lds_w6[2 + c][mt][lane];
        acc[mt] = __builtin_amdgcn_mfma_f32_32x32x16_bf16(
            __builtin_bit_cast(bf16x8, a), b, acc[mt], 0, 0, 0);
      }
    }
    // Chunk 12: bias.
#pragma unroll
    for (int mt = 0; mt < 2; ++mt)
      acc[mt] = __builtin_amdgcn_mfma_f32_32x32x16_bf16(
          __builtin_bit_cast(bf16x8, make_uint4(a12[mt], 0u, 0u, 0u)),
          __builtin_bit_cast(bf16x8, b13u), acc[mt], 0, 0, 0);

    // Epilogue: relu + We2 dot (We2 broadcast from LDS).
    // acc[mt][4g+q] -> hidden row o = mt*32 + q + 8g + 4*half.
    float s = 0.f;
#pragma unroll
    for (int mt = 0; mt < 2; ++mt)
#pragma unroll
      for (int g = 0; g < 4; ++g) {
        const float4 ew = *(const float4*)&lds_c[mt * 32 + g * 8 + 4 * half];
        s += fmaxf(acc[mt][4 * g + 0], 0.f) * ew.x;
        s += fmaxf(acc[mt][4 * g + 1], 0.f) * ew.y;
        s += fmaxf(acc[mt][4 * g + 2], 0.f) * ew.z;
        s += fmaxf(acc[mt][4 * g + 3], 0.f) * ew.w;
      }
    s += __shfl_xor(s, 32);
    if (half == 0) out[t * 32 + n] = s + be2v;
  };

  int t = wid;
  body(t, TrueTag{});
  for (t += nw; t < ntiles; t += nw) body(t, FalseTag{});
}

extern "C" void kernel_launch(void* const* d_in, const int* in_sizes, int n_in,
                              void* d_out, int out_size, void* d_ws,
                              size_t ws_size, hipStream_t stream) {
  const float* X = (const float*)d_in[0];
  const int* pairs = (const int*)d_in[1];
  const float* W1 = (const float*)d_in[2];
  const float* b1 = (const float*)d_in[3];
  const float* W2 = (const float*)d_in[4];
  const float* b2 = (const float*)d_in[5];
  const float* We1 = (const float*)d_in[6];
  const float* be1 = (const float*)d_in[7];
  const float* We2 = (const float*)d_in[8];
  const float* be2 = (const float*)d_in[9];
  float* out = (float*)d_out;
  unsigned short* H = (unsigned short*)d_ws;  // 100000*64 bf16 = 12.8 MB

  node_mfma_kernel<<<3125, 64, 0, stream>>>(X, W1, b1, W2, b2, H);
  // 76.25 KB LDS/block -> 2 blocks/CU. Actual reg usage ~108 total <= 128
  // -> HW occupancy 16 waves/CU (4/SIMD); bound (512,3) only guarantees no
  // spill (budget ~170, need ~108).
  edge_mlp_kernel<<<512, 512, 0, stream>>>(H, pairs, We1, be1, We2, be2, out);
}